// Round 16
// baseline (3313.372 us; speedup 1.0000x reference)
//
#include <hip/hip_runtime.h>

// 2-layer LSTM (H=256, T=256, B=512, I=2) + linear head.
// R16: 256 blocks x 256 threads, 1 wave/SIMD (__launch_bounds__(256,1) ->
// ~450-VGPR budget; R15 falsified the "parking always spills" rule: the
// 64-reg cap was an NT=1024 occupancy-incentive artifact, gone when LDS
// forces 1 block/CU). Thread owns ALL 4 gate rows of unit u (i,f,g,o) x
// 2 batches -> cell updates fully thread-local, gbuf deleted (gates carried
// in registers across the t-loop), freed LDS -> 9 LDS-parked chunks.
// Parking: 19 chunks in VGPRs (304 regs) + 9 in LDS (144 KB) -> 68/96
// streamed (68 % 4 == 0, stable 4-buffer rotation).
// Chunks stored as 4 gate-planes of 4 KB (16 B/lane: coalesced global,
// conflict-free LDS). Merged-phase loop (R13): one 96-chunk gemm/step,
// 2 lgkm-only barriers, h single-buffered, y deferred 1 step.
// Spill detector: FETCH_SIZE (GB-scale = scratch thrash -> reduce NVP).
// Round-3 lesson: no cross-block exchange.

typedef float vf2 __attribute__((ext_vector_type(2)));
typedef _Float16 vh2 __attribute__((ext_vector_type(2)));
typedef _Float16 vh4 __attribute__((ext_vector_type(4)));
typedef _Float16 vh8 __attribute__((ext_vector_type(8)));

#define NT 256
#define TSTEPS 256
#define NCH 96            // logical chunks per step (chunk = 8 k x 1024 rows)
#define NSTRM 68          // streamed chunks per step
#define NVP 19            // VGPR-parked chunks (positions 68..86)
#define NLP 9             // LDS-parked chunks  (positions 87..95)
#define CHB 16384         // bytes per chunk
#define FS 393216         // fp32 table offset (floats) = 96*CHB/4

__global__ void prep_kernel(const float* __restrict__ W_ih1,
                            const float* __restrict__ W_hh1,
                            const float* __restrict__ b_ih1,
                            const float* __restrict__ b_hh1,
                            const float* __restrict__ W_ih2,
                            const float* __restrict__ W_hh2,
                            const float* __restrict__ b_ih2,
                            const float* __restrict__ b_hh2,
                            void* __restrict__ ws) {
    const int stride = gridDim.x * blockDim.x;
    const int idx = blockIdx.x * blockDim.x + threadIdx.x;
    _Float16* wh = (_Float16*)ws;
    float* wf = (float*)ws;
    // chunk ch (0..95) covers k = 8*ch..8*ch+7 for all 1024 gate-rows.
    // k<256: W_hh1 | k<512: W_ih2 | else W_hh2.
    // In-chunk layout: 4 gate-planes of 2048 fp16; fp16 idx =
    //   g*2048 + u*8 + i, row = g*256+u, k = 8*ch+i.
    // (16 B/lane for 256 threads -> coalesced global, conflict-free LDS.)
    // Identity chunk order: 0..67 streamed, 68..86 VGPR, 87..95 LDS.
    for (int e = idx; e < NCH * 8192; e += stride) {
        int ch = e >> 13, rem = e & 8191;
        int g = rem >> 11, u = (rem >> 3) & 255, i = rem & 7;
        int row = (g << 8) + u;
        int k = (ch << 3) + i;
        float v;
        if (k < 256)      v = W_hh1[row * 256 + k];
        else if (k < 512) v = W_ih2[row * 256 + (k - 256)];
        else              v = W_hh2[row * 256 + (k - 512)];
        wh[e] = (_Float16)v;
    }
    for (int j = idx; j < 1024; j += stride) {
        wf[FS + j]        = W_ih1[j * 2 + 0];
        wf[FS + 1024 + j] = W_ih1[j * 2 + 1];
        wf[FS + 2048 + j] = b_ih1[j] + b_hh1[j];
        wf[FS + 3072 + j] = b_ih2[j] + b_hh2[j];
    }
}

__device__ __forceinline__ float sig_(float v) {
    return 1.f / (1.f + __expf(-v));
}
__device__ __forceinline__ float tanh_(float v) {
    return 1.f - 2.f / (__expf(2.f * v) + 1.f);
}
__device__ __forceinline__ float fdot2_(vh2 a, vh2 b, float c) {
#if __has_builtin(__builtin_amdgcn_fdot2)
    return __builtin_amdgcn_fdot2(a, b, c, false);
#else
    return c + (float)a.x * (float)b.x + (float)a.y * (float)b.y;
#endif
}

union W8 { vh8 v; vh2 p[4]; };
struct WQuad { vh8 a, b, c, d; };   // gate rows i,f,g,o of unit u, 8 k each

// lgkm-only barrier: LDS drained, weight-stream vmem stays in flight.
#define BARRIER() __asm__ volatile("s_waitcnt lgkmcnt(0)\ns_barrier" ::: "memory")

__global__ __launch_bounds__(NT, 1) void lstm_kernel(
    const float* __restrict__ x,      // (512, 256, 2)
    const void* __restrict__ ws,
    const float* __restrict__ W_lin,  // (2, 256)
    const float* __restrict__ b_lin,  // (2,)
    float* __restrict__ out)          // (512, 256, 2)
{
    __shared__ _Float16 h1s[2][256];           // h1 [batch][unit]
    __shared__ _Float16 h2s[2][256];           // h2
    __shared__ char lds_park[NLP][CHB];        // 9 parked chunks (144 KB)

    const int tid = threadIdx.x;
    const int u = tid;                         // owned unit (4 gate rows)
    const int b0 = blockIdx.x * 2;
    const char* wstream = (const char*)ws;
    const float* wtab = (const float*)ws;

    // per-unit W_ih1 columns and fused biases, all 4 gates
    const float wxi0 = wtab[FS + u],        wxf0 = wtab[FS + 256 + u];
    const float wxg0 = wtab[FS + 512 + u],  wxo0 = wtab[FS + 768 + u];
    const float wxi1 = wtab[FS + 1024 + u], wxf1 = wtab[FS + 1280 + u];
    const float wxg1 = wtab[FS + 1536 + u], wxo1 = wtab[FS + 1792 + u];
    const float bi1 = wtab[FS + 2048 + u],  bf1 = wtab[FS + 2304 + u];
    const float bg1 = wtab[FS + 2560 + u],  bo1 = wtab[FS + 2816 + u];
    const float bi2 = wtab[FS + 3072 + u],  bf2 = wtab[FS + 3328 + u];
    const float bg2 = wtab[FS + 3584 + u],  bo2 = wtab[FS + 3840 + u];

    // y-head: wave wv (0..3) -> (batch ob, output oo); lane covers 4 units
    const int lane = tid & 63, wv = tid >> 6;
    const int ob = wv >> 1, oo = wv & 1;
    const float wl0 = W_lin[oo * 256 + 4 * lane + 0];
    const float wl1 = W_lin[oo * 256 + 4 * lane + 1];
    const float wl2 = W_lin[oo * 256 + 4 * lane + 2];
    const float wl3 = W_lin[oo * 256 + 4 * lane + 3];
    const float blin = b_lin[oo];

    for (int i = tid; i < 512; i += NT) {
        ((_Float16*)h1s)[i] = (_Float16)0.f;
        ((_Float16*)h2s)[i] = (_Float16)0.f;
    }

    float c1a = 0.f, c1b = 0.f, c2a = 0.f, c2b = 0.f;

    const int t16 = tid * 16;
    int sp = 0;                                // uniform stream byte offset

    auto loadc = [&](WQuad& d) {
        const char* p = wstream + sp + t16;
        d.a = *(const vh8*)p;
        d.b = *(const vh8*)(p + 4096);
        d.c = *(const vh8*)(p + 8192);
        d.d = *(const vh8*)(p + 12288);
        sp += CHB;
        if (sp == NSTRM * CHB) sp = 0;
    };
    // acc order: [0]=i.b0 [1]=i.b1 [2]=f.b0 [3]=f.b1 [4]=g.b0 [5]=g.b1 [6]=o.b0 [7]=o.b1
    auto usec = [&](const WQuad& w, const _Float16 (*hp)[256], int k0,
                    float (&A)[8]) {
        W8 wi; wi.v = w.a;  W8 wff; wff.v = w.b;
        W8 wg; wg.v = w.c;  W8 wo;  wo.v  = w.d;
        W8 ha; ha.v = *(const vh8*)&hp[0][k0];
        W8 hb; hb.v = *(const vh8*)&hp[1][k0];
        #pragma unroll
        for (int m = 0; m < 4; ++m) {
            A[0] = fdot2_(wi.p[m],  ha.p[m], A[0]);
            A[1] = fdot2_(wi.p[m],  hb.p[m], A[1]);
            A[2] = fdot2_(wff.p[m], ha.p[m], A[2]);
            A[3] = fdot2_(wff.p[m], hb.p[m], A[3]);
            A[4] = fdot2_(wg.p[m],  ha.p[m], A[4]);
            A[5] = fdot2_(wg.p[m],  hb.p[m], A[5]);
            A[6] = fdot2_(wo.p[m],  ha.p[m], A[6]);
            A[7] = fdot2_(wo.p[m],  hb.p[m], A[7]);
        }
    };

    // stage LDS-parked chunks (positions 87..95)
    for (int s = 0; s < NLP; ++s) {
        const char* src = wstream + (size_t)(NSTRM + NVP + s) * CHB + t16;
        *(vh8*)&lds_park[s][t16]         = *(const vh8*)src;
        *(vh8*)&lds_park[s][4096 + t16]  = *(const vh8*)(src + 4096);
        *(vh8*)&lds_park[s][8192 + t16]  = *(const vh8*)(src + 8192);
        *(vh8*)&lds_park[s][12288 + t16] = *(const vh8*)(src + 12288);
    }

    // VGPR-parked chunks (positions 68..86): hh2 k = 32..183
    WQuad wreg[NVP];
    #pragma unroll
    for (int s = 0; s < NVP; ++s) {
        const char* src = wstream + (size_t)(NSTRM + s) * CHB + t16;
        wreg[s].a = *(const vh8*)src;
        wreg[s].b = *(const vh8*)(src + 4096);
        wreg[s].c = *(const vh8*)(src + 8192);
        wreg[s].d = *(const vh8*)(src + 12288);
    }

    // prologue: gates1(0) = b1 + Wih1*x(0)   (h1(-1)=0)
    float P[8], Q[8];
    {
        vf2 x0a = *(const vf2*)(x + (size_t)(b0 + 0) * 512);
        vf2 x0b = *(const vf2*)(x + (size_t)(b0 + 1) * 512);
        P[0] = bi1 + wxi0 * x0a.x + wxi1 * x0a.y;
        P[1] = bi1 + wxi0 * x0b.x + wxi1 * x0b.y;
        P[2] = bf1 + wxf0 * x0a.x + wxf1 * x0a.y;
        P[3] = bf1 + wxf0 * x0b.x + wxf1 * x0b.y;
        P[4] = bg1 + wxg0 * x0a.x + wxg1 * x0a.y;
        P[5] = bg1 + wxg0 * x0b.x + wxg1 * x0b.y;
        P[6] = bo1 + wxo0 * x0a.x + wxo1 * x0a.y;
        P[7] = bo1 + wxo0 * x0b.x + wxo1 * x0b.y;
    }
    vf2 xv0 = *(const vf2*)(x + (size_t)(b0 + 0) * 512 + 2);   // x(1)
    vf2 xv1 = *(const vf2*)(x + (size_t)(b0 + 1) * 512 + 2);

    WQuad bA, bB, bC, bD;
    loadc(bA); loadc(bB); loadc(bC); loadc(bD);
    __syncthreads();   // init barrier (full drain once is fine)

    auto gemm32 = [&](const _Float16 (*hp)[256], float (&A)[8]) {
        #pragma unroll 1
        for (int q = 0; q < 32; q += 4) {
            usec(bA, hp, 8 * q,      A); loadc(bA);
            usec(bB, hp, 8 * q + 8,  A); loadc(bB);
            usec(bC, hp, 8 * q + 16, A); loadc(bC);
            usec(bD, hp, 8 * q + 24, A); loadc(bD);
        }
    };

    #pragma unroll 1
    for (int t = 0; t < TSTEPS; ++t) {
        // ---- U1: layer-1 cell update -> h1(t)  (fully thread-local) ----
        c1a = sig_(P[2]) * c1a + sig_(P[0]) * tanh_(P[4]);
        c1b = sig_(P[3]) * c1b + sig_(P[1]) * tanh_(P[5]);
        h1s[0][u] = (_Float16)(sig_(P[6]) * tanh_(c1a));
        h1s[1][u] = (_Float16)(sig_(P[7]) * tanh_(c1b));
        BARRIER();   // B1: h1(t) visible; h2(t-1) (from prev U2) visible

        // ---- y(t-1) (deferred; h2(t-1) stable in this epoch) ----
        if (t > 0) {
            vh4 hv = *(const vh4*)&h2s[ob][4 * lane];
            float s = (float)hv.x * wl0 + (float)hv.y * wl1
                    + (float)hv.z * wl2 + (float)hv.w * wl3;
            #pragma unroll
            for (int m = 32; m >= 1; m >>= 1) s += __shfl_xor(s, m, 64);
            if (lane == 0)
                out[(size_t)(b0 + ob) * 512 + (t - 1) * 2 + oo] = s + blin;
        }

        // ---- one unbroken 96-chunk gemm ----
        // gates1(t+1): b1 + Wih1*x(t+1) + Whh1*h1(t)   [streamed 0..31]
        P[0] = bi1 + wxi0 * xv0.x + wxi1 * xv0.y;
        P[1] = bi1 + wxi0 * xv1.x + wxi1 * xv1.y;
        P[2] = bf1 + wxf0 * xv0.x + wxf1 * xv0.y;
        P[3] = bf1 + wxf0 * xv1.x + wxf1 * xv1.y;
        P[4] = bg1 + wxg0 * xv0.x + wxg1 * xv0.y;
        P[5] = bg1 + wxg0 * xv1.x + wxg1 * xv1.y;
        P[6] = bo1 + wxo0 * xv0.x + wxo1 * xv0.y;
        P[7] = bo1 + wxo0 * xv1.x + wxo1 * xv1.y;
        {   // prefetch x(t+2) (wraps harmlessly)
            const int tn = (t + 2) & (TSTEPS - 1);
            xv0 = *(const vf2*)(x + (size_t)(b0 + 0) * 512 + tn * 2);
            xv1 = *(const vf2*)(x + (size_t)(b0 + 1) * 512 + tn * 2);
        }
        gemm32(h1s, P);

        // gates2(t): b2 + Wih2*h1(t) [streamed 32..63]
        //          + Whh2*h2(t-1)    [streamed 64..67 = k 0..31,
        //                             VGPR parks k 32..183, LDS parks k 184..255]
        Q[0] = bi2; Q[1] = bi2; Q[2] = bf2; Q[3] = bf2;
        Q[4] = bg2; Q[5] = bg2; Q[6] = bo2; Q[7] = bo2;
        gemm32(h1s, Q);
        usec(bA, h2s, 0,  Q); loadc(bA);
        usec(bB, h2s, 8,  Q); loadc(bB);
        usec(bC, h2s, 16, Q); loadc(bC);
        usec(bD, h2s, 24, Q); loadc(bD);
        #pragma unroll
        for (int s = 0; s < NVP; ++s)
            usec(wreg[s], h2s, 32 + 8 * s, Q);
        #pragma unroll 1
        for (int s = 0; s < NLP; ++s) {
            WQuad w;
            w.a = *(const vh8*)&lds_park[s][t16];
            w.b = *(const vh8*)&lds_park[s][4096 + t16];
            w.c = *(const vh8*)&lds_park[s][8192 + t16];
            w.d = *(const vh8*)&lds_park[s][12288 + t16];
            usec(w, h2s, 184 + 8 * s, Q);
        }
        BARRIER();   // B2: all gemm reads of h1s/h2s complete

        // ---- U2: layer-2 cell update -> h2(t)  (fully thread-local) ----
        c2a = sig_(Q[2]) * c2a + sig_(Q[0]) * tanh_(Q[4]);
        c2b = sig_(Q[3]) * c2b + sig_(Q[1]) * tanh_(Q[5]);
        h2s[0][u] = (_Float16)(sig_(Q[6]) * tanh_(c2a));
        h2s[1][u] = (_Float16)(sig_(Q[7]) * tanh_(c2b));
        // no barrier: next iteration's B1 publishes h2(t) before it's read
    }

    // ---- tail: y(255) ----
    BARRIER();
    {
        vh4 hv = *(const vh4*)&h2s[ob][4 * lane];
        float s = (float)hv.x * wl0 + (float)hv.y * wl1
                + (float)hv.z * wl2 + (float)hv.w * wl3;
        #pragma unroll
        for (int m = 32; m >= 1; m >>= 1) s += __shfl_xor(s, m, 64);
        if (lane == 0)
            out[(size_t)(b0 + ob) * 512 + 255 * 2 + oo] = s + blin;
    }
}

extern "C" void kernel_launch(void* const* d_in, const int* in_sizes, int n_in,
                              void* d_out, int out_size, void* d_ws, size_t ws_size,
                              hipStream_t stream) {
    const float* x     = (const float*)d_in[0];
    const float* W_ih1 = (const float*)d_in[1];
    const float* W_hh1 = (const float*)d_in[2];
    const float* b_ih1 = (const float*)d_in[3];
    const float* b_hh1 = (const float*)d_in[4];
    const float* W_ih2 = (const float*)d_in[5];
    const float* W_hh2 = (const float*)d_in[6];
    const float* b_ih2 = (const float*)d_in[7];
    const float* b_hh2 = (const float*)d_in[8];
    const float* W_lin = (const float*)d_in[9];
    const float* b_lin = (const float*)d_in[10];
    float* out = (float*)d_out;

    prep_kernel<<<256, 256, 0, stream>>>(W_ih1, W_hh1, b_ih1, b_hh1,
                                         W_ih2, W_hh2, b_ih2, b_hh2, d_ws);
    lstm_kernel<<<256, NT, 0, stream>>>(x, d_ws, W_lin, b_lin, out);
}

// Round 17
// 3033.485 us; speedup vs baseline: 1.0923x; 1.0923x over previous
//
#include <hip/hip_runtime.h>

// 2-layer LSTM (H=256, T=256, B=512, I=2) + linear head.
// 256 blocks x 512 threads (2 waves/SIMD - needed for latency hiding,
// R16 showed 1 wave/SIMD loses its parking gain to exposed stalls).
// R17: VGPR parks are PINNED via empty asm("":"+v") on each lane - the asm
// becomes the def, so the compiler cannot rematerialize the park into
// per-step L2 reloads (R16 post-mortem: VGPR_Count 228 < park size proved
// silent remat; L2 reloads are invisible in FETCH_SIZE which counts HBM).
// Parking: 16 chunks pinned in VGPRs (128 regs; 88 base + 128 = 216 <=
// 256-reg cap at 2 waves/SIMD) + 8 chunks in LDS (128 KB) -> 72/96
// streamed (72 % 4 == 0, stable 4-buffer rotation).
// Kept from R13/R15: merged-phase loop (one 96-chunk gemm/step, 2
// lgkm-only barriers, h single-buffered, y deferred 1 step), thread owns
// 2 gate-rows (tid, tid+512) x 2 batches, LDS parks as two 8KB planes
// (16 B/lane conflict-free), compact rolled loops for streaming, h fp16
// in LDS (broadcast reads), c in regs, fdot2 via union views.
// Round-3 lesson: no cross-block exchange. Spill detector: FETCH_SIZE.

typedef float vf2 __attribute__((ext_vector_type(2)));
typedef _Float16 vh2 __attribute__((ext_vector_type(2)));
typedef _Float16 vh4 __attribute__((ext_vector_type(4)));
typedef _Float16 vh8 __attribute__((ext_vector_type(8)));

#define NT 512
#define TSTEPS 256
#define NCH 96            // logical chunks per step (chunk = 8 k x 1024 rows)
#define NSTRM 72          // streamed chunks per step
#define NVP 16            // VGPR-parked chunks (positions 72..87)
#define NLP 8             // LDS-parked chunks  (positions 88..95)
#define CHB 16384         // bytes per chunk
#define FS 393216         // fp32 table offset (floats) = 96*CHB/4

__global__ void prep_kernel(const float* __restrict__ W_ih1,
                            const float* __restrict__ W_hh1,
                            const float* __restrict__ b_ih1,
                            const float* __restrict__ b_hh1,
                            const float* __restrict__ W_ih2,
                            const float* __restrict__ W_hh2,
                            const float* __restrict__ b_ih2,
                            const float* __restrict__ b_hh2,
                            void* __restrict__ ws) {
    const int stride = gridDim.x * blockDim.x;
    const int idx = blockIdx.x * blockDim.x + threadIdx.x;
    _Float16* wh = (_Float16*)ws;
    float* wf = (float*)ws;
    // chunk ch (0..95) covers k = 8*ch..8*ch+7 for all 1024 gate-rows.
    // k<256: W_hh1 | k<512: W_ih2 | else W_hh2. Identity order:
    // 0..71 streamed, 72..87 VGPR-parked, 88..95 LDS-parked.
    // streamed/VGPR layout: fp16 idx = th*16 + r*8 + i  (thread th reads
    //   rows {th, th+512} as 2 vh8 at byte th*32).
    // LDS-park layout: two 8KB planes, idx = r*4096 + th*8 + i
    //   (16 B/lane stride per plane -> conflict-free LDS access).
    for (int e = idx; e < NCH * 8192; e += stride) {
        int ch = e >> 13, rem = e & 8191;
        int th, r, i;
        if (ch >= NSTRM + NVP) { r = rem >> 12; th = (rem >> 3) & 511; i = rem & 7; }
        else                   { th = rem >> 4; r = (rem >> 3) & 1;    i = rem & 7; }
        int row = th + (r << 9);
        int k = (ch << 3) + i;
        float v;
        if (k < 256)      v = W_hh1[row * 256 + k];
        else if (k < 512) v = W_ih2[row * 256 + (k - 256)];
        else              v = W_hh2[row * 256 + (k - 512)];
        wh[e] = (_Float16)v;
    }
    for (int j = idx; j < 1024; j += stride) {
        wf[FS + j]        = W_ih1[j * 2 + 0];
        wf[FS + 1024 + j] = W_ih1[j * 2 + 1];
        wf[FS + 2048 + j] = b_ih1[j] + b_hh1[j];
        wf[FS + 3072 + j] = b_ih2[j] + b_hh2[j];
    }
}

__device__ __forceinline__ float sig_(float v) {
    return 1.f / (1.f + __expf(-v));
}
__device__ __forceinline__ float tanh_(float v) {
    return 1.f - 2.f / (__expf(2.f * v) + 1.f);
}
__device__ __forceinline__ float fdot2_(vh2 a, vh2 b, float c) {
#if __has_builtin(__builtin_amdgcn_fdot2)
    return __builtin_amdgcn_fdot2(a, b, c, false);
#else
    return c + (float)a.x * (float)b.x + (float)a.y * (float)b.y;
#endif
}

union W8 { vh8 v; vh2 p[4]; };
struct WPair { vh8 r0, r1; };   // rows tid and tid+512, 8 k each

// lgkm-only barrier: LDS drained, weight-stream vmem stays in flight.
#define BARRIER() __asm__ volatile("s_waitcnt lgkmcnt(0)\ns_barrier" ::: "memory")

__global__ __launch_bounds__(NT, 2) void lstm_kernel(
    const float* __restrict__ x,      // (512, 256, 2)
    const void* __restrict__ ws,
    const float* __restrict__ W_lin,  // (2, 256)
    const float* __restrict__ b_lin,  // (2,)
    float* __restrict__ out)          // (512, 256, 2)
{
    __shared__ float g1buf[2][1024];           // gates1 preacts [batch][row]
    __shared__ float g2buf[2][1024];           // gates2 preacts
    __shared__ _Float16 h1s[2][256];           // h1 [batch][unit] (single-buf)
    __shared__ _Float16 h2s[2][256];           // h2
    __shared__ char lds_park[NLP][CHB];        // 8 parked chunks (128 KB)

    const int tid = threadIdx.x;
    const int j = tid;                         // owned rows j and j+512
    const int u = tid & 255, bu = tid >> 8;    // cell-update: unit u, batch bu
    const int b0 = blockIdx.x * 2;
    const char* wstream = (const char*)ws;
    const float* wf = (const float*)ws;

    const float wx0a = wf[FS + j],        wx1a = wf[FS + 1024 + j];
    const float wx0b = wf[FS + 512 + j],  wx1b = wf[FS + 1536 + j];
    const float bj1a = wf[FS + 2048 + j], bj1b = wf[FS + 2560 + j];
    const float bj2a = wf[FS + 3072 + j], bj2b = wf[FS + 3584 + j];

    // y-head: waves 0..3 -> (batch ob, output oo); lane covers 4 units
    const int lane = tid & 63, wv = tid >> 6;
    const int ob = (wv >> 1) & 1, oo = wv & 1;
    const float wl0 = W_lin[oo * 256 + 4 * lane + 0];
    const float wl1 = W_lin[oo * 256 + 4 * lane + 1];
    const float wl2 = W_lin[oo * 256 + 4 * lane + 2];
    const float wl3 = W_lin[oo * 256 + 4 * lane + 3];
    const float blin = b_lin[oo];

    // zero initial h (512 threads cover 2*256 each array)
    ((_Float16*)h1s)[tid] = (_Float16)0.f;
    ((_Float16*)h2s)[tid] = (_Float16)0.f;

    float c1 = 0.f, c2 = 0.f;

    const int t16 = tid * 16, t32 = tid * 32;
    int sp = 0;                                // uniform stream byte offset

    auto loadc = [&](WPair& d) {
        d.r0 = *(const vh8*)(wstream + sp + t32);
        d.r1 = *(const vh8*)(wstream + sp + t32 + 16);
        sp += CHB;
        if (sp == NSTRM * CHB) sp = 0;
    };
    auto usec = [&](const WPair& w, const _Float16 (*hp)[256], int k0,
                    float& A00, float& A01, float& A10, float& A11) {
        W8 u0; u0.v = w.r0;
        W8 u1; u1.v = w.r1;
        W8 ha; ha.v = *(const vh8*)&hp[0][k0];
        W8 hb; hb.v = *(const vh8*)&hp[1][k0];
        A00 = fdot2_(u0.p[0], ha.p[0], A00); A00 = fdot2_(u0.p[1], ha.p[1], A00);
        A00 = fdot2_(u0.p[2], ha.p[2], A00); A00 = fdot2_(u0.p[3], ha.p[3], A00);
        A01 = fdot2_(u0.p[0], hb.p[0], A01); A01 = fdot2_(u0.p[1], hb.p[1], A01);
        A01 = fdot2_(u0.p[2], hb.p[2], A01); A01 = fdot2_(u0.p[3], hb.p[3], A01);
        A10 = fdot2_(u1.p[0], ha.p[0], A10); A10 = fdot2_(u1.p[1], ha.p[1], A10);
        A10 = fdot2_(u1.p[2], ha.p[2], A10); A10 = fdot2_(u1.p[3], ha.p[3], A10);
        A11 = fdot2_(u1.p[0], hb.p[0], A11); A11 = fdot2_(u1.p[1], hb.p[1], A11);
        A11 = fdot2_(u1.p[2], hb.p[2], A11); A11 = fdot2_(u1.p[3], hb.p[3], A11);
    };

    // stage LDS-parked chunks (positions 88..95; two 8KB planes each)
    for (int s = 0; s < NLP; ++s) {
        const char* src = wstream + (size_t)(NSTRM + NVP + s) * CHB;
        *(vh8*)&lds_park[s][t16]        = *(const vh8*)(src + t16);
        *(vh8*)&lds_park[s][8192 + t16] = *(const vh8*)(src + 8192 + t16);
    }

    // VGPR-parked chunks (positions 72..87): hh2 k = 64..191.
    // PINNED: empty asm is the def of each lane -> no rematerialization.
    WPair wreg[NVP];
    #pragma unroll
    for (int s = 0; s < NVP; ++s) {
        const char* src = wstream + (size_t)(NSTRM + s) * CHB + t32;
        union { vh8 v; float f[4]; } p0, p1;
        p0.v = *(const vh8*)src;
        p1.v = *(const vh8*)(src + 16);
        asm volatile("" : "+v"(p0.f[0]), "+v"(p0.f[1]),
                          "+v"(p0.f[2]), "+v"(p0.f[3]),
                          "+v"(p1.f[0]), "+v"(p1.f[1]),
                          "+v"(p1.f[2]), "+v"(p1.f[3]));
        wreg[s].r0 = p0.v;
        wreg[s].r1 = p1.v;
    }

    // prologue: gates1(0) = b1 + Wih1*x(0)  (h1(-1)=0: no gemm term)
    {
        vf2 x0a = *(const vf2*)(x + (size_t)(b0 + 0) * 512);
        vf2 x0b = *(const vf2*)(x + (size_t)(b0 + 1) * 512);
        g1buf[0][j]       = bj1a + wx0a * x0a.x + wx1a * x0a.y;
        g1buf[1][j]       = bj1a + wx0a * x0b.x + wx1a * x0b.y;
        g1buf[0][512 + j] = bj1b + wx0b * x0a.x + wx1b * x0a.y;
        g1buf[1][512 + j] = bj1b + wx0b * x0b.x + wx1b * x0b.y;
    }
    vf2 xv0 = *(const vf2*)(x + (size_t)(b0 + 0) * 512 + 2);   // x(1)
    vf2 xv1 = *(const vf2*)(x + (size_t)(b0 + 1) * 512 + 2);

    WPair bA, bB, bC, bD;
    loadc(bA); loadc(bB); loadc(bC); loadc(bD);
    __syncthreads();   // init barrier (full drain once is fine)

    auto gemm32 = [&](const _Float16 (*hp)[256],
                      float& A00, float& A01, float& A10, float& A11) {
        #pragma unroll 1
        for (int q = 0; q < 32; q += 4) {
            usec(bA, hp, 8 * q,      A00, A01, A10, A11); loadc(bA);
            usec(bB, hp, 8 * q + 8,  A00, A01, A10, A11); loadc(bB);
            usec(bC, hp, 8 * q + 16, A00, A01, A10, A11); loadc(bC);
            usec(bD, hp, 8 * q + 24, A00, A01, A10, A11); loadc(bD);
        }
    };
    auto gemm8 = [&](const _Float16 (*hp)[256],
                     float& A00, float& A01, float& A10, float& A11) {
        #pragma unroll 1
        for (int q = 0; q < 8; q += 4) {
            usec(bA, hp, 8 * q,      A00, A01, A10, A11); loadc(bA);
            usec(bB, hp, 8 * q + 8,  A00, A01, A10, A11); loadc(bB);
            usec(bC, hp, 8 * q + 16, A00, A01, A10, A11); loadc(bC);
            usec(bD, hp, 8 * q + 24, A00, A01, A10, A11); loadc(bD);
        }
    };

    #pragma unroll 1
    for (int t = 0; t < TSTEPS; ++t) {
        // ---- U1: layer-1 cell update -> h1(t)  (reads g1buf = gates1(t)) ----
        {
            float gi = sig_(g1buf[bu][u]);
            float gf = sig_(g1buf[bu][256 + u]);
            float gg = tanh_(g1buf[bu][512 + u]);
            float go = sig_(g1buf[bu][768 + u]);
            c1 = gf * c1 + gi * gg;
            h1s[bu][u] = (_Float16)(go * tanh_(c1));
        }
        BARRIER();   // B1: h1(t) visible; h2(t-1) (from prev U2) visible

        // ---- y(t-1) (deferred; h2(t-1) stable in this epoch) ----
        if (t > 0 && wv < 4) {
            vh4 hv = *(const vh4*)&h2s[ob][4 * lane];
            float s = (float)hv.x * wl0 + (float)hv.y * wl1
                    + (float)hv.z * wl2 + (float)hv.w * wl3;
            #pragma unroll
            for (int m = 32; m >= 1; m >>= 1) s += __shfl_xor(s, m, 64);
            if (lane == 0)
                out[(size_t)(b0 + ob) * 512 + (t - 1) * 2 + oo] = s + blin;
        }

        // ---- one unbroken 96-chunk gemm ----
        // gates1(t+1): b1 + Wih1*x(t+1) + Whh1*h1(t)   [streamed 0..31]
        float a00 = bj1a + wx0a * xv0.x + wx1a * xv0.y;
        float a01 = bj1a + wx0a * xv1.x + wx1a * xv1.y;
        float a10 = bj1b + wx0b * xv0.x + wx1b * xv0.y;
        float a11 = bj1b + wx0b * xv1.x + wx1b * xv1.y;
        {   // prefetch x(t+2) (wraps harmlessly)
            const int tn = (t + 2) & (TSTEPS - 1);
            xv0 = *(const vf2*)(x + (size_t)(b0 + 0) * 512 + tn * 2);
            xv1 = *(const vf2*)(x + (size_t)(b0 + 1) * 512 + tn * 2);
        }
        gemm32(h1s, a00, a01, a10, a11);
        g1buf[0][j] = a00; g1buf[1][j] = a01;
        g1buf[0][512 + j] = a10; g1buf[1][512 + j] = a11;

        // gates2(t): b2 + Wih2*h1(t) [streamed 32..63]
        //          + Whh2*h2(t-1)    [streamed 64..71 = k 0..63,
        //                             VGPR parks k 64..191, LDS parks k 192..255]
        a00 = bj2a; a01 = bj2a; a10 = bj2b; a11 = bj2b;
        gemm32(h1s, a00, a01, a10, a11);
        gemm8(h2s, a00, a01, a10, a11);
        #pragma unroll
        for (int s = 0; s < NVP; ++s)
            usec(wreg[s], h2s, 64 + 8 * s, a00, a01, a10, a11);
        #pragma unroll 1
        for (int s = 0; s < NLP; ++s) {
            WPair w;
            w.r0 = *(const vh8*)&lds_park[s][t16];
            w.r1 = *(const vh8*)&lds_park[s][8192 + t16];
            usec(w, h2s, 192 + 8 * s, a00, a01, a10, a11);
        }
        g2buf[0][j] = a00; g2buf[1][j] = a01;
        g2buf[0][512 + j] = a10; g2buf[1][512 + j] = a11;
        BARRIER();   // B2: g1buf/g2buf visible

        // ---- U2: layer-2 cell update -> h2(t) ----
        {
            float gi = sig_(g2buf[bu][u]);
            float gf = sig_(g2buf[bu][256 + u]);
            float gg = tanh_(g2buf[bu][512 + u]);
            float go = sig_(g2buf[bu][768 + u]);
            c2 = gf * c2 + gi * gg;
            h2s[bu][u] = (_Float16)(go * tanh_(c2));
        }
        // no barrier: next iteration's B1 publishes h2(t) before it's read
    }

    // ---- tail: y(255) ----
    BARRIER();
    if (wv < 4) {
        vh4 hv = *(const vh4*)&h2s[ob][4 * lane];
        float s = (float)hv.x * wl0 + (float)hv.y * wl1
                + (float)hv.z * wl2 + (float)hv.w * wl3;
        #pragma unroll
        for (int m = 32; m >= 1; m >>= 1) s += __shfl_xor(s, m, 64);
        if (lane == 0)
            out[(size_t)(b0 + ob) * 512 + 255 * 2 + oo] = s + blin;
    }
}

extern "C" void kernel_launch(void* const* d_in, const int* in_sizes, int n_in,
                              void* d_out, int out_size, void* d_ws, size_t ws_size,
                              hipStream_t stream) {
    const float* x     = (const float*)d_in[0];
    const float* W_ih1 = (const float*)d_in[1];
    const float* W_hh1 = (const float*)d_in[2];
    const float* b_ih1 = (const float*)d_in[3];
    const float* b_hh1 = (const float*)d_in[4];
    const float* W_ih2 = (const float*)d_in[5];
    const float* W_hh2 = (const float*)d_in[6];
    const float* b_ih2 = (const float*)d_in[7];
    const float* b_hh2 = (const float*)d_in[8];
    const float* W_lin = (const float*)d_in[9];
    const float* b_lin = (const float*)d_in[10];
    float* out = (float*)d_out;

    prep_kernel<<<256, 256, 0, stream>>>(W_ih1, W_hh1, b_ih1, b_hh1,
                                         W_ih2, W_hh2, b_ih2, b_hh2, d_ws);
    lstm_kernel<<<256, NT, 0, stream>>>(x, d_ws, W_lin, b_lin, out);
}

// Round 18
// 3008.556 us; speedup vs baseline: 1.1013x; 1.0083x over previous
//
#include <hip/hip_runtime.h>

// 2-layer LSTM (H=256, T=256, B=512, I=2) + linear head.
// 256 blocks x 512 threads (2 waves/SIMD), 2 batches/block, t-loop in-kernel.
// R18: NVP 16 -> 20 (160 park regs + ~70 base <= 256-reg cap @ 2 waves/SIMD).
// 68/96 chunks streamed (68 % 4 == 0). VGPR parks PINNED via empty
// asm("":"+v") defs (R17: prevents silent rematerialization into L2
// reloads; parks may live in AGPRs via the gfx950 unified file - fine,
// accvgpr moves are VALU-cheap). 8 chunks LDS-parked (128 KB, two 8KB
// planes, 16 B/lane conflict-free). Fitted model R11-R17:
// dur = ~1290us + 24.2us x streamed_chunks -> predict ~2930.
// Kept: merged-phase loop (one 96-chunk gemm/step, 2 lgkm-only barriers,
// h single-buffered, y deferred 1 step), thread owns 2 gate-rows
// (tid, tid+512) x 2 batches, compact rolled loops for streaming
// (R7-R10: big unrolled schedules spill), h fp16 in LDS (broadcast
// reads), c in regs, fdot2 via union views.
// Round-3 lesson: no cross-block exchange. Spill detector: FETCH_SIZE.

typedef float vf2 __attribute__((ext_vector_type(2)));
typedef _Float16 vh2 __attribute__((ext_vector_type(2)));
typedef _Float16 vh4 __attribute__((ext_vector_type(4)));
typedef _Float16 vh8 __attribute__((ext_vector_type(8)));

#define NT 512
#define TSTEPS 256
#define NCH 96            // logical chunks per step (chunk = 8 k x 1024 rows)
#define NSTRM 68          // streamed chunks per step
#define NVP 20            // VGPR-parked chunks (positions 68..87)
#define NLP 8             // LDS-parked chunks  (positions 88..95)
#define CHB 16384         // bytes per chunk
#define FS 393216         // fp32 table offset (floats) = 96*CHB/4

__global__ void prep_kernel(const float* __restrict__ W_ih1,
                            const float* __restrict__ W_hh1,
                            const float* __restrict__ b_ih1,
                            const float* __restrict__ b_hh1,
                            const float* __restrict__ W_ih2,
                            const float* __restrict__ W_hh2,
                            const float* __restrict__ b_ih2,
                            const float* __restrict__ b_hh2,
                            void* __restrict__ ws) {
    const int stride = gridDim.x * blockDim.x;
    const int idx = blockIdx.x * blockDim.x + threadIdx.x;
    _Float16* wh = (_Float16*)ws;
    float* wf = (float*)ws;
    // chunk ch (0..95) covers k = 8*ch..8*ch+7 for all 1024 gate-rows.
    // k<256: W_hh1 | k<512: W_ih2 | else W_hh2. Identity order:
    // 0..67 streamed, 68..87 VGPR-parked, 88..95 LDS-parked.
    // streamed/VGPR layout: fp16 idx = th*16 + r*8 + i  (thread th reads
    //   rows {th, th+512} as 2 vh8 at byte th*32).
    // LDS-park layout: two 8KB planes, idx = r*4096 + th*8 + i
    //   (16 B/lane stride per plane -> conflict-free LDS access).
    for (int e = idx; e < NCH * 8192; e += stride) {
        int ch = e >> 13, rem = e & 8191;
        int th, r, i;
        if (ch >= NSTRM + NVP) { r = rem >> 12; th = (rem >> 3) & 511; i = rem & 7; }
        else                   { th = rem >> 4; r = (rem >> 3) & 1;    i = rem & 7; }
        int row = th + (r << 9);
        int k = (ch << 3) + i;
        float v;
        if (k < 256)      v = W_hh1[row * 256 + k];
        else if (k < 512) v = W_ih2[row * 256 + (k - 256)];
        else              v = W_hh2[row * 256 + (k - 512)];
        wh[e] = (_Float16)v;
    }
    for (int j = idx; j < 1024; j += stride) {
        wf[FS + j]        = W_ih1[j * 2 + 0];
        wf[FS + 1024 + j] = W_ih1[j * 2 + 1];
        wf[FS + 2048 + j] = b_ih1[j] + b_hh1[j];
        wf[FS + 3072 + j] = b_ih2[j] + b_hh2[j];
    }
}

__device__ __forceinline__ float sig_(float v) {
    return 1.f / (1.f + __expf(-v));
}
__device__ __forceinline__ float tanh_(float v) {
    return 1.f - 2.f / (__expf(2.f * v) + 1.f);
}
__device__ __forceinline__ float fdot2_(vh2 a, vh2 b, float c) {
#if __has_builtin(__builtin_amdgcn_fdot2)
    return __builtin_amdgcn_fdot2(a, b, c, false);
#else
    return c + (float)a.x * (float)b.x + (float)a.y * (float)b.y;
#endif
}

union W8 { vh8 v; vh2 p[4]; };
struct WPair { vh8 r0, r1; };   // rows tid and tid+512, 8 k each

// lgkm-only barrier: LDS drained, weight-stream vmem stays in flight.
#define BARRIER() __asm__ volatile("s_waitcnt lgkmcnt(0)\ns_barrier" ::: "memory")

__global__ __launch_bounds__(NT, 2) void lstm_kernel(
    const float* __restrict__ x,      // (512, 256, 2)
    const void* __restrict__ ws,
    const float* __restrict__ W_lin,  // (2, 256)
    const float* __restrict__ b_lin,  // (2,)
    float* __restrict__ out)          // (512, 256, 2)
{
    __shared__ float g1buf[2][1024];           // gates1 preacts [batch][row]
    __shared__ float g2buf[2][1024];           // gates2 preacts
    __shared__ _Float16 h1s[2][256];           // h1 [batch][unit] (single-buf)
    __shared__ _Float16 h2s[2][256];           // h2
    __shared__ char lds_park[NLP][CHB];        // 8 parked chunks (128 KB)

    const int tid = threadIdx.x;
    const int j = tid;                         // owned rows j and j+512
    const int u = tid & 255, bu = tid >> 8;    // cell-update: unit u, batch bu
    const int b0 = blockIdx.x * 2;
    const char* wstream = (const char*)ws;
    const float* wf = (const float*)ws;

    const float wx0a = wf[FS + j],        wx1a = wf[FS + 1024 + j];
    const float wx0b = wf[FS + 512 + j],  wx1b = wf[FS + 1536 + j];
    const float bj1a = wf[FS + 2048 + j], bj1b = wf[FS + 2560 + j];
    const float bj2a = wf[FS + 3072 + j], bj2b = wf[FS + 3584 + j];

    // y-head: waves 0..3 -> (batch ob, output oo); lane covers 4 units
    const int lane = tid & 63, wv = tid >> 6;
    const int ob = (wv >> 1) & 1, oo = wv & 1;
    const float wl0 = W_lin[oo * 256 + 4 * lane + 0];
    const float wl1 = W_lin[oo * 256 + 4 * lane + 1];
    const float wl2 = W_lin[oo * 256 + 4 * lane + 2];
    const float wl3 = W_lin[oo * 256 + 4 * lane + 3];
    const float blin = b_lin[oo];

    // zero initial h (512 threads cover 2*256 each array)
    ((_Float16*)h1s)[tid] = (_Float16)0.f;
    ((_Float16*)h2s)[tid] = (_Float16)0.f;

    float c1 = 0.f, c2 = 0.f;

    const int t16 = tid * 16, t32 = tid * 32;
    int sp = 0;                                // uniform stream byte offset

    auto loadc = [&](WPair& d) {
        d.r0 = *(const vh8*)(wstream + sp + t32);
        d.r1 = *(const vh8*)(wstream + sp + t32 + 16);
        sp += CHB;
        if (sp == NSTRM * CHB) sp = 0;
    };
    auto usec = [&](const WPair& w, const _Float16 (*hp)[256], int k0,
                    float& A00, float& A01, float& A10, float& A11) {
        W8 u0; u0.v = w.r0;
        W8 u1; u1.v = w.r1;
        W8 ha; ha.v = *(const vh8*)&hp[0][k0];
        W8 hb; hb.v = *(const vh8*)&hp[1][k0];
        A00 = fdot2_(u0.p[0], ha.p[0], A00); A00 = fdot2_(u0.p[1], ha.p[1], A00);
        A00 = fdot2_(u0.p[2], ha.p[2], A00); A00 = fdot2_(u0.p[3], ha.p[3], A00);
        A01 = fdot2_(u0.p[0], hb.p[0], A01); A01 = fdot2_(u0.p[1], hb.p[1], A01);
        A01 = fdot2_(u0.p[2], hb.p[2], A01); A01 = fdot2_(u0.p[3], hb.p[3], A01);
        A10 = fdot2_(u1.p[0], ha.p[0], A10); A10 = fdot2_(u1.p[1], ha.p[1], A10);
        A10 = fdot2_(u1.p[2], ha.p[2], A10); A10 = fdot2_(u1.p[3], ha.p[3], A10);
        A11 = fdot2_(u1.p[0], hb.p[0], A11); A11 = fdot2_(u1.p[1], hb.p[1], A11);
        A11 = fdot2_(u1.p[2], hb.p[2], A11); A11 = fdot2_(u1.p[3], hb.p[3], A11);
    };

    // stage LDS-parked chunks (positions 88..95; two 8KB planes each)
    for (int s = 0; s < NLP; ++s) {
        const char* src = wstream + (size_t)(NSTRM + NVP + s) * CHB;
        *(vh8*)&lds_park[s][t16]        = *(const vh8*)(src + t16);
        *(vh8*)&lds_park[s][8192 + t16] = *(const vh8*)(src + 8192 + t16);
    }

    // VGPR-parked chunks (positions 68..87): hh2 k = 32..191.
    // PINNED: empty asm is the def of each lane -> no rematerialization.
    WPair wreg[NVP];
    #pragma unroll
    for (int s = 0; s < NVP; ++s) {
        const char* src = wstream + (size_t)(NSTRM + s) * CHB + t32;
        union { vh8 v; float f[4]; } p0, p1;
        p0.v = *(const vh8*)src;
        p1.v = *(const vh8*)(src + 16);
        asm volatile("" : "+v"(p0.f[0]), "+v"(p0.f[1]),
                          "+v"(p0.f[2]), "+v"(p0.f[3]),
                          "+v"(p1.f[0]), "+v"(p1.f[1]),
                          "+v"(p1.f[2]), "+v"(p1.f[3]));
        wreg[s].r0 = p0.v;
        wreg[s].r1 = p1.v;
    }

    // prologue: gates1(0) = b1 + Wih1*x(0)  (h1(-1)=0: no gemm term)
    {
        vf2 x0a = *(const vf2*)(x + (size_t)(b0 + 0) * 512);
        vf2 x0b = *(const vf2*)(x + (size_t)(b0 + 1) * 512);
        g1buf[0][j]       = bj1a + wx0a * x0a.x + wx1a * x0a.y;
        g1buf[1][j]       = bj1a + wx0a * x0b.x + wx1a * x0b.y;
        g1buf[0][512 + j] = bj1b + wx0b * x0a.x + wx1b * x0a.y;
        g1buf[1][512 + j] = bj1b + wx0b * x0b.x + wx1b * x0b.y;
    }
    vf2 xv0 = *(const vf2*)(x + (size_t)(b0 + 0) * 512 + 2);   // x(1)
    vf2 xv1 = *(const vf2*)(x + (size_t)(b0 + 1) * 512 + 2);

    WPair bA, bB, bC, bD;
    loadc(bA); loadc(bB); loadc(bC); loadc(bD);
    __syncthreads();   // init barrier (full drain once is fine)

    auto gemm32 = [&](const _Float16 (*hp)[256],
                      float& A00, float& A01, float& A10, float& A11) {
        #pragma unroll 1
        for (int q = 0; q < 32; q += 4) {
            usec(bA, hp, 8 * q,      A00, A01, A10, A11); loadc(bA);
            usec(bB, hp, 8 * q + 8,  A00, A01, A10, A11); loadc(bB);
            usec(bC, hp, 8 * q + 16, A00, A01, A10, A11); loadc(bC);
            usec(bD, hp, 8 * q + 24, A00, A01, A10, A11); loadc(bD);
        }
    };

    #pragma unroll 1
    for (int t = 0; t < TSTEPS; ++t) {
        // ---- U1: layer-1 cell update -> h1(t)  (reads g1buf = gates1(t)) ----
        {
            float gi = sig_(g1buf[bu][u]);
            float gf = sig_(g1buf[bu][256 + u]);
            float gg = tanh_(g1buf[bu][512 + u]);
            float go = sig_(g1buf[bu][768 + u]);
            c1 = gf * c1 + gi * gg;
            h1s[bu][u] = (_Float16)(go * tanh_(c1));
        }
        BARRIER();   // B1: h1(t) visible; h2(t-1) (from prev U2) visible

        // ---- y(t-1) (deferred; h2(t-1) stable in this epoch) ----
        if (t > 0 && wv < 4) {
            vh4 hv = *(const vh4*)&h2s[ob][4 * lane];
            float s = (float)hv.x * wl0 + (float)hv.y * wl1
                    + (float)hv.z * wl2 + (float)hv.w * wl3;
            #pragma unroll
            for (int m = 32; m >= 1; m >>= 1) s += __shfl_xor(s, m, 64);
            if (lane == 0)
                out[(size_t)(b0 + ob) * 512 + (t - 1) * 2 + oo] = s + blin;
        }

        // ---- one unbroken 96-chunk gemm ----
        // gates1(t+1): b1 + Wih1*x(t+1) + Whh1*h1(t)   [streamed 0..31]
        float a00 = bj1a + wx0a * xv0.x + wx1a * xv0.y;
        float a01 = bj1a + wx0a * xv1.x + wx1a * xv1.y;
        float a10 = bj1b + wx0b * xv0.x + wx1b * xv0.y;
        float a11 = bj1b + wx0b * xv1.x + wx1b * xv1.y;
        {   // prefetch x(t+2) (wraps harmlessly)
            const int tn = (t + 2) & (TSTEPS - 1);
            xv0 = *(const vf2*)(x + (size_t)(b0 + 0) * 512 + tn * 2);
            xv1 = *(const vf2*)(x + (size_t)(b0 + 1) * 512 + tn * 2);
        }
        gemm32(h1s, a00, a01, a10, a11);
        g1buf[0][j] = a00; g1buf[1][j] = a01;
        g1buf[0][512 + j] = a10; g1buf[1][512 + j] = a11;

        // gates2(t): b2 + Wih2*h1(t) [streamed 32..63]
        //          + Whh2*h2(t-1)    [streamed 64..67 = k 0..31,
        //                             VGPR parks k 32..191, LDS parks k 192..255]
        a00 = bj2a; a01 = bj2a; a10 = bj2b; a11 = bj2b;
        gemm32(h1s, a00, a01, a10, a11);
        usec(bA, h2s, 0,  a00, a01, a10, a11); loadc(bA);
        usec(bB, h2s, 8,  a00, a01, a10, a11); loadc(bB);
        usec(bC, h2s, 16, a00, a01, a10, a11); loadc(bC);
        usec(bD, h2s, 24, a00, a01, a10, a11); loadc(bD);
        #pragma unroll
        for (int s = 0; s < NVP; ++s)
            usec(wreg[s], h2s, 32 + 8 * s, a00, a01, a10, a11);
        #pragma unroll 1
        for (int s = 0; s < NLP; ++s) {
            WPair w;
            w.r0 = *(const vh8*)&lds_park[s][t16];
            w.r1 = *(const vh8*)&lds_park[s][8192 + t16];
            usec(w, h2s, 192 + 8 * s, a00, a01, a10, a11);
        }
        g2buf[0][j] = a00; g2buf[1][j] = a01;
        g2buf[0][512 + j] = a10; g2buf[1][512 + j] = a11;
        BARRIER();   // B2: g1buf/g2buf visible

        // ---- U2: layer-2 cell update -> h2(t) ----
        {
            float gi = sig_(g2buf[bu][u]);
            float gf = sig_(g2buf[bu][256 + u]);
            float gg = tanh_(g2buf[bu][512 + u]);
            float go = sig_(g2buf[bu][768 + u]);
            c2 = gf * c2 + gi * gg;
            h2s[bu][u] = (_Float16)(go * tanh_(c2));
        }
        // no barrier: next iteration's B1 publishes h2(t) before it's read
    }

    // ---- tail: y(255) ----
    BARRIER();
    if (wv < 4) {
        vh4 hv = *(const vh4*)&h2s[ob][4 * lane];
        float s = (float)hv.x * wl0 + (float)hv.y * wl1
                + (float)hv.z * wl2 + (float)hv.w * wl3;
        #pragma unroll
        for (int m = 32; m >= 1; m >>= 1) s += __shfl_xor(s, m, 64);
        if (lane == 0)
            out[(size_t)(b0 + ob) * 512 + 255 * 2 + oo] = s + blin;
    }
}

extern "C" void kernel_launch(void* const* d_in, const int* in_sizes, int n_in,
                              void* d_out, int out_size, void* d_ws, size_t ws_size,
                              hipStream_t stream) {
    const float* x     = (const float*)d_in[0];
    const float* W_ih1 = (const float*)d_in[1];
    const float* W_hh1 = (const float*)d_in[2];
    const float* b_ih1 = (const float*)d_in[3];
    const float* b_hh1 = (const float*)d_in[4];
    const float* W_ih2 = (const float*)d_in[5];
    const float* W_hh2 = (const float*)d_in[6];
    const float* b_ih2 = (const float*)d_in[7];
    const float* b_hh2 = (const float*)d_in[8];
    const float* W_lin = (const float*)d_in[9];
    const float* b_lin = (const float*)d_in[10];
    float* out = (float*)d_out;

    prep_kernel<<<256, 256, 0, stream>>>(W_ih1, W_hh1, b_ih1, b_hh1,
                                         W_ih2, W_hh2, b_ih2, b_hh2, d_ws);
    lstm_kernel<<<256, NT, 0, stream>>>(x, d_ws, W_lin, b_lin, out);
}